// Round 4
// baseline (502.672 us; speedup 1.0000x reference)
//
#include <hip/hip_runtime.h>
#include <hip/hip_bf16.h>

typedef __bf16 v8bf __attribute__((ext_vector_type(8)));
typedef float  v4f  __attribute__((ext_vector_type(4)));
typedef unsigned int v4u __attribute__((ext_vector_type(4)));

#define B_ROWS 16384
#define NSLOTS 32768
#define MAXTILES 264
#define CSTRIDE 136   // C-stage LDS row stride (bf16) -> 272 B, 16B-aligned rows

// ---- workspace layout (bytes) ----
#define OFF_W1T   0u                    // [8][1024][512] bf16
#define OFF_W2T   8388608u              // [8][512][1024] bf16
#define OFF_W3T   16777216u             // [8][256][512] bf16
#define OFF_W4T   18874368u             // [8][32][256] bf16
#define OFF_META  19005440u             // ints, 4KB
#define OFF_SEL   19009536u             // int[16384]
#define OFF_W01   19075072u             // float2[16384]; reused as int2 invmap after scatter
#define OFF_ROWL  19206144u             // int[32768]
#define OFF_WL    19337216u             // float[32768]
#define OFF_Q     19468288u             // union region: G1+G2 | H2 | EO
#define OFF_G1    OFF_Q                 // [16384][256] f32
#define OFF_G2    (OFF_Q + 16777216u)   // [16384][128] f32
#define OFF_H2    OFF_Q                 // [32768][512] bf16
#define OFF_EO    OFF_Q                 // [32768][32] f32 (after H2 dead)
#define OFF_H1    (OFF_Q + 33554432u)   // [32768][1024] bf16  (H3 aliases)
#define OFF_H3    OFF_H1                // [32768][256] bf16
#define WS_NEED   (OFF_H1 + 67108864u)

// meta[] int layout: [0]=n_tiles [1..8]=counts [9..16]=cursor [17..24]=base
// [32..295]=tile_expert [296..559]=tile_m0 [560..823]=tile_rows

__device__ __forceinline__ void gload_lds16(const void* g, void* l) {
  __builtin_amdgcn_global_load_lds(
      (const __attribute__((address_space(1))) void*)g,
      (__attribute__((address_space(3))) void*)l, 16, 0, 0);
}

__device__ __forceinline__ float elu_f(float x) {
  return x > 0.f ? x : expm1f(x);
}

// ---- all weight transposes fp32 [E][R][C] -> bf16 [E][C][R] in one launch ----
__global__ __launch_bounds__(256) void transpose_all(
    const float* __restrict__ ew1, const float* __restrict__ ew2,
    const float* __restrict__ ew3, const float* __restrict__ ew4,
    __hip_bfloat16* __restrict__ W1T, __hip_bfloat16* __restrict__ W2T,
    __hip_bfloat16* __restrict__ W3T, __hip_bfloat16* __restrict__ W4T) {
  __shared__ __align__(16) float tile[32][33];
  int b = blockIdx.x;
  const float* src; __hip_bfloat16* dst; int R, C, gxs, tps, idx;
  if (b < 4096)      { src = ew1; dst = W1T; R = 512;  C = 1024; gxs = 4; tps = 9; idx = b; }
  else if (b < 8192) { src = ew2; dst = W2T; R = 1024; C = 512;  gxs = 5; tps = 9; idx = b - 4096; }
  else if (b < 9216) { src = ew3; dst = W3T; R = 512;  C = 256;  gxs = 4; tps = 7; idx = b - 8192; }
  else               { src = ew4; dst = W4T; R = 256;  C = 32;   gxs = 3; tps = 3; idx = b - 9216; }
  int e = idx >> tps, tt = idx & ((1 << tps) - 1);
  int r0 = (tt & ((1 << gxs) - 1)) * 32, c0 = (tt >> gxs) * 32;
  src += (size_t)e * R * C;
  dst += (size_t)e * R * C;
  int tr = threadIdx.x >> 5, tc = threadIdx.x & 31;
#pragma unroll
  for (int q = 0; q < 4; ++q)
    tile[tr + 8*q][tc] = src[(size_t)(r0 + tr + 8*q) * C + c0 + tc];
  __syncthreads();
#pragma unroll
  for (int q = 0; q < 4; ++q)
    dst[(size_t)(c0 + tr + 8*q) * R + r0 + tc] = __float2bfloat16(tile[tc][tr + 8*q]);
}

// ---- fp32 SGEMM + bias + ELU: C[M][N] = elu(A[M][K] @ B[K][N] + bias) ----
__global__ __launch_bounds__(256) void sgemm_elu(
    const float* __restrict__ A, const float* __restrict__ Bm,
    const float* __restrict__ bias, float* __restrict__ C,
    int M, int N, int K) {
  __shared__ __align__(16) float sA[16][132];
  __shared__ __align__(16) float sB[16][68];
  int tid = threadIdx.x;
  int tx = tid & 15, ty = tid >> 4;
  int m0 = blockIdx.x * 128, n0 = blockIdx.y * 64;
  float acc[8][4] = {};
  for (int k0 = 0; k0 < K; k0 += 16) {
    {
      int m = tid >> 1, ks = (tid & 1) * 8;
      const float* ap = &A[(size_t)(m0 + m) * K + k0 + ks];
      float4 v0 = *(const float4*)ap;
      float4 v1 = *(const float4*)(ap + 4);
      sA[ks+0][m] = v0.x; sA[ks+1][m] = v0.y; sA[ks+2][m] = v0.z; sA[ks+3][m] = v0.w;
      sA[ks+4][m] = v1.x; sA[ks+5][m] = v1.y; sA[ks+6][m] = v1.z; sA[ks+7][m] = v1.w;
    }
    {
      int kr = tid >> 4, nn = (tid & 15) * 4;
      *(float4*)&sB[kr][nn] = *(const float4*)&Bm[(size_t)(k0 + kr) * N + n0 + nn];
    }
    __syncthreads();
#pragma unroll
    for (int kk = 0; kk < 16; ++kk) {
      float a[8], b[4];
      *(float4*)&a[0] = *(const float4*)&sA[kk][ty*8];
      *(float4*)&a[4] = *(const float4*)&sA[kk][ty*8+4];
      *(float4*)&b[0] = *(const float4*)&sB[kk][tx*4];
#pragma unroll
      for (int i = 0; i < 8; ++i)
#pragma unroll
        for (int j = 0; j < 4; ++j)
          acc[i][j] = fmaf(a[i], b[j], acc[i][j]);
    }
    __syncthreads();
  }
  float bs[4];
#pragma unroll
  for (int j = 0; j < 4; ++j) bs[j] = bias[n0 + tx*4 + j];
#pragma unroll
  for (int i = 0; i < 8; ++i) {
    int m = m0 + ty*8 + i;
    float4 o;
    o.x = elu_f(acc[i][0] + bs[0]);
    o.y = elu_f(acc[i][1] + bs[1]);
    o.z = elu_f(acc[i][2] + bs[2]);
    o.w = elu_f(acc[i][3] + bs[3]);
    *(float4*)&C[(size_t)m * N + n0 + tx*4] = o;
  }
}

// ---- gate layer 3 + softmax + top2 + renorm + counts ----
__global__ __launch_bounds__(256) void gate3_topk(
    const float* __restrict__ G2, const float* __restrict__ gw3,
    const float* __restrict__ gb3, int* __restrict__ sel01,
    float2* __restrict__ w01, int* __restrict__ meta) {
  __shared__ __align__(16) float g2t[64][132];
  __shared__ __align__(16) float w3[1024];
  __shared__ float b3[8];
  __shared__ int lc[8];
  int tid = threadIdx.x;
  int row0 = blockIdx.x * 64;
  {
    int r = tid >> 5, f = (tid & 31) * 4;
#pragma unroll
    for (int rr = 0; rr < 64; rr += 8)
      *(float4*)&g2t[r + rr][f] = *(const float4*)&G2[(size_t)(row0 + r + rr) * 128 + f];
  }
  ((float4*)w3)[tid] = ((const float4*)gw3)[tid];
  if (tid < 8) { b3[tid] = gb3[tid]; lc[tid] = 0; }
  __syncthreads();
  if (tid < 64) {
    int row = row0 + tid;
    float lg[8];
#pragma unroll
    for (int e = 0; e < 8; ++e) lg[e] = b3[e];
    for (int k = 0; k < 128; ++k) {
      float x = g2t[tid][k];
#pragma unroll
      for (int e = 0; e < 8; ++e) lg[e] = fmaf(x, w3[k*8 + e], lg[e]);
    }
    float mx = lg[0];
#pragma unroll
    for (int e = 1; e < 8; ++e) mx = fmaxf(mx, lg[e]);
    float p[8], s = 0.f;
#pragma unroll
    for (int e = 0; e < 8; ++e) { p[e] = expf(lg[e] - mx); s += p[e]; }
    float inv = 1.f / s;
#pragma unroll
    for (int e = 0; e < 8; ++e) p[e] *= inv;
    int i0 = 0; float v0 = p[0];
#pragma unroll
    for (int e = 1; e < 8; ++e) if (p[e] > v0) { v0 = p[e]; i0 = e; }
    int i1 = -1; float v1 = -1.f;
#pragma unroll
    for (int e = 0; e < 8; ++e) if (e != i0 && p[e] > v1) { v1 = p[e]; i1 = e; }
    float sw = 1.f / (v0 + v1);
    sel01[row] = i0 | (i1 << 8);
    w01[row] = make_float2(v0 * sw, v1 * sw);
    atomicAdd(&lc[i0], 1);
    atomicAdd(&lc[i1], 1);
  }
  __syncthreads();
  if (tid < 8) atomicAdd(&meta[1 + tid], lc[tid]);
}

// ---- prefix + tile table (single thread) ----
__global__ void build_tiles(int* __restrict__ meta) {
  if (threadIdx.x != 0) return;
  int base = 0, nt = 0;
  for (int e = 0; e < 8; ++e) {
    int c = meta[1 + e];
    meta[17 + e] = base;
    for (int j = 0; j < c; j += 128) {
      meta[32 + nt]  = e;
      meta[296 + nt] = base + j;
      meta[560 + nt] = (c - j < 128) ? (c - j) : 128;
      nt++;
    }
    base += c;
  }
  meta[0] = nt;
}

// ---- scatter rows into per-expert slot lists; also emit row->slots inverse map ----
__global__ __launch_bounds__(256) void scatter_rows(
    const int* __restrict__ sel01, float2* __restrict__ w01,
    int* __restrict__ meta, int* __restrict__ rowlist, float* __restrict__ wlist) {
  __shared__ int lc[8];
  __shared__ int gb[8];
  int tid = threadIdx.x;
  if (tid < 8) lc[tid] = 0;
  __syncthreads();
  int row = blockIdx.x * 256 + tid;
  int s = sel01[row];
  int e0 = s & 255, e1 = (s >> 8) & 255;
  float2 w = w01[row];
  int l0 = atomicAdd(&lc[e0], 1);
  int l1 = atomicAdd(&lc[e1], 1);
  __syncthreads();
  if (tid < 8) gb[tid] = atomicAdd(&meta[9 + tid], lc[tid]);
  __syncthreads();
  int s0 = meta[17 + e0] + gb[e0] + l0;
  int s1 = meta[17 + e1] + gb[e1] + l1;
  rowlist[s0] = row; wlist[s0] = w.x;
  rowlist[s1] = row; wlist[s1] = w.y;
  ((int2*)w01)[row] = make_int2(s0, s1);
}

// ================= grouped MFMA GEMM (L2/L3): bf16 A from global =================
// C[slot][N] = elu(A[slot][K] @ BT[e][N][K]^T + bias[e][N]); 128x128 tile, BK=32.
// grid = (N/128, MAXTILES) so n-blocks of one tile dispatch adjacently.
// Epilogue staged through LDS -> 16B nontemporal stores.
__global__ __launch_bounds__(256) void moe_gemm(
    const __hip_bfloat16* __restrict__ A, const __hip_bfloat16* __restrict__ BT,
    const float* __restrict__ bias, __hip_bfloat16* __restrict__ C,
    const int* __restrict__ meta, int N, int K) {
  int t = blockIdx.y;
  if (t >= meta[0]) return;
  int e    = meta[32 + t];
  int m0   = meta[296 + t];
  int rows = meta[560 + t];
  int n0   = blockIdx.x * 128;

  __shared__ __align__(16) char smem[CSTRIDE * 128 * 2 > 16384 ? CSTRIDE * 128 * 2 : 16384];
  __hip_bfloat16* sA  = (__hip_bfloat16*)smem;          // 8 KB
  __hip_bfloat16* sB  = (__hip_bfloat16*)(smem + 8192); // 8 KB
  __hip_bfloat16* cst = (__hip_bfloat16*)smem;          // epilogue stage (aliases sA/sB)

  int tid = threadIdx.x;
  int w = tid >> 6, l = tid & 63;
  int lr = l >> 2;
  int lk = (l & 3) * 8;
  int wm = w >> 1, wn = w & 1;
  int ml = l & 15, kq = l >> 4;

  const __hip_bfloat16* BTe = BT + (size_t)e * N * K;
  v4f acc[4][4] = {};

  for (int k0 = 0; k0 < K; k0 += 32) {
#pragma unroll
    for (int it = 0; it < 2; ++it) {
      int r = it * 64 + w * 16 + lr;
      int gr = m0 + (r < rows ? r : rows - 1);
      gload_lds16(A + (size_t)gr * K + k0 + lk, &sA[(it * 64 + w * 16) * 32]);
    }
#pragma unroll
    for (int it = 0; it < 2; ++it) {
      int r = it * 64 + w * 16 + lr;
      gload_lds16(BTe + (size_t)(n0 + r) * K + k0 + lk, &sB[(it * 64 + w * 16) * 32]);
    }
    __syncthreads();
    v8bf af[4], bf[4];
#pragma unroll
    for (int i = 0; i < 4; ++i)
      af[i] = *(const v8bf*)&sA[(wm * 64 + i * 16 + ml) * 32 + kq * 8];
#pragma unroll
    for (int j = 0; j < 4; ++j)
      bf[j] = *(const v8bf*)&sB[(wn * 64 + j * 16 + ml) * 32 + kq * 8];
#pragma unroll
    for (int i = 0; i < 4; ++i)
#pragma unroll
      for (int j = 0; j < 4; ++j)
        acc[i][j] = __builtin_amdgcn_mfma_f32_16x16x32_bf16(af[i], bf[j], acc[i][j], 0, 0, 0);
    __syncthreads();
  }

  // bias per (wn, j, ml)
  float bs[4];
#pragma unroll
  for (int j = 0; j < 4; ++j)
    bs[j] = bias[(size_t)e * N + n0 + wn * 64 + j * 16 + ml];

  // staged epilogue: two 64-row phases; waves with wm==h produce, all store out
#pragma unroll
  for (int h = 0; h < 2; ++h) {
    if (wm == h) {
#pragma unroll
      for (int i = 0; i < 4; ++i)
#pragma unroll
        for (int j = 0; j < 4; ++j)
#pragma unroll
          for (int r = 0; r < 4; ++r)
            cst[(i * 16 + kq * 4 + r) * CSTRIDE + wn * 64 + j * 16 + ml] =
                __float2bfloat16(elu_f(acc[i][j][r] + bs[j]));
    }
    __syncthreads();
#pragma unroll
    for (int q = 0; q < 4; ++q) {
      int z = q * 256 + tid;
      int row = z >> 4, ch = z & 15;
      int rl = h * 64 + row;
      if (rl < rows) {
        v4u v = *(const v4u*)&cst[row * CSTRIDE + ch * 8];
        __builtin_nontemporal_store(
            v, (v4u*)&C[(size_t)(m0 + rl) * N + n0 + ch * 8]);
      }
    }
    __syncthreads();
  }
}

// ================= L1 GEMM with fused row gather (fp32 obs -> bf16 LDS) =========
__global__ __launch_bounds__(256) void moe_gemm_l1(
    const float* __restrict__ obs, const __hip_bfloat16* __restrict__ BT,
    const float* __restrict__ bias, __hip_bfloat16* __restrict__ C,
    const int* __restrict__ rowlist, const int* __restrict__ meta, int N, int K) {
  int t = blockIdx.y;
  if (t >= meta[0]) return;
  int e    = meta[32 + t];
  int m0   = meta[296 + t];
  int rows = meta[560 + t];
  int n0   = blockIdx.x * 128;

  __shared__ __align__(16) char smem[CSTRIDE * 128 * 2 > 16384 ? CSTRIDE * 128 * 2 : 16384];
  __hip_bfloat16* sA  = (__hip_bfloat16*)smem;
  __hip_bfloat16* sB  = (__hip_bfloat16*)(smem + 8192);
  __hip_bfloat16* cst = (__hip_bfloat16*)smem;

  int tid = threadIdx.x;
  int w = tid >> 6, l = tid & 63;
  int lr = l >> 2;
  int lk = (l & 3) * 8;
  int wm = w >> 1, wn = w & 1;
  int ml = l & 15, kq = l >> 4;

  // per-thread gather source: row = tid>>1, half = tid&1 (16 floats each)
  int arow = (tid >> 1) < rows ? (tid >> 1) : rows - 1;
  const float* aptr =
      obs + (size_t)(rowlist[m0 + arow] & (B_ROWS - 1)) * 512 + (tid & 1) * 16;
  v4u* sAdst = (v4u*)&sA[(tid >> 1) * 32 + (tid & 1) * 16];

  const __hip_bfloat16* BTe = BT + (size_t)e * N * K;
  v4f acc[4][4] = {};

  for (int k0 = 0; k0 < K; k0 += 32) {
    // A: gather fp32 16 floats -> bf16x16 -> 2x ds_write_b128
    float4 g0 = *(const float4*)(aptr + k0);
    float4 g1 = *(const float4*)(aptr + k0 + 4);
    float4 g2 = *(const float4*)(aptr + k0 + 8);
    float4 g3 = *(const float4*)(aptr + k0 + 12);
    union { __hip_bfloat16 h[16]; v4u u[2]; } pk;
    pk.h[0]  = __float2bfloat16(g0.x); pk.h[1]  = __float2bfloat16(g0.y);
    pk.h[2]  = __float2bfloat16(g0.z); pk.h[3]  = __float2bfloat16(g0.w);
    pk.h[4]  = __float2bfloat16(g1.x); pk.h[5]  = __float2bfloat16(g1.y);
    pk.h[6]  = __float2bfloat16(g1.z); pk.h[7]  = __float2bfloat16(g1.w);
    pk.h[8]  = __float2bfloat16(g2.x); pk.h[9]  = __float2bfloat16(g2.y);
    pk.h[10] = __float2bfloat16(g2.z); pk.h[11] = __float2bfloat16(g2.w);
    pk.h[12] = __float2bfloat16(g3.x); pk.h[13] = __float2bfloat16(g3.y);
    pk.h[14] = __float2bfloat16(g3.z); pk.h[15] = __float2bfloat16(g3.w);
    sAdst[0] = pk.u[0];
    sAdst[1] = pk.u[1];
    // B: async global->LDS
#pragma unroll
    for (int it = 0; it < 2; ++it) {
      int r = it * 64 + w * 16 + lr;
      gload_lds16(BTe + (size_t)(n0 + r) * K + k0 + lk, &sB[(it * 64 + w * 16) * 32]);
    }
    __syncthreads();
    v8bf af[4], bf[4];
#pragma unroll
    for (int i = 0; i < 4; ++i)
      af[i] = *(const v8bf*)&sA[(wm * 64 + i * 16 + ml) * 32 + kq * 8];
#pragma unroll
    for (int j = 0; j < 4; ++j)
      bf[j] = *(const v8bf*)&sB[(wn * 64 + j * 16 + ml) * 32 + kq * 8];
#pragma unroll
    for (int i = 0; i < 4; ++i)
#pragma unroll
      for (int j = 0; j < 4; ++j)
        acc[i][j] = __builtin_amdgcn_mfma_f32_16x16x32_bf16(af[i], bf[j], acc[i][j], 0, 0, 0);
    __syncthreads();
  }

  float bs[4];
#pragma unroll
  for (int j = 0; j < 4; ++j)
    bs[j] = bias[(size_t)e * N + n0 + wn * 64 + j * 16 + ml];

#pragma unroll
  for (int h = 0; h < 2; ++h) {
    if (wm == h) {
#pragma unroll
      for (int i = 0; i < 4; ++i)
#pragma unroll
        for (int j = 0; j < 4; ++j)
#pragma unroll
          for (int r = 0; r < 4; ++r)
            cst[(i * 16 + kq * 4 + r) * CSTRIDE + wn * 64 + j * 16 + ml] =
                __float2bfloat16(elu_f(acc[i][j][r] + bs[j]));
    }
    __syncthreads();
#pragma unroll
    for (int q = 0; q < 4; ++q) {
      int z = q * 256 + tid;
      int row = z >> 4, ch = z & 15;
      int rl = h * 64 + row;
      if (rl < rows) {
        v4u v = *(const v4u*)&cst[row * CSTRIDE + ch * 8];
        __builtin_nontemporal_store(
            v, (v4u*)&C[(size_t)(m0 + rl) * N + n0 + ch * 8]);
      }
    }
    __syncthreads();
  }
}

// ---- L4 as grouped MFMA GEMM: EO[slot][32] = H3[slot][256] @ W4T[e][32][256]^T + eb4 ----
__global__ __launch_bounds__(256) void l4_gemm(
    const __hip_bfloat16* __restrict__ H3, const __hip_bfloat16* __restrict__ W4T,
    const float* __restrict__ eb4, const int* __restrict__ meta,
    float* __restrict__ EO) {
  int t = blockIdx.x;
  if (t >= meta[0]) return;
  int e = meta[32 + t], m0 = meta[296 + t], rows = meta[560 + t];
  __shared__ __align__(16) __hip_bfloat16 sW[32 * 264];
  int tid = threadIdx.x;
  {
    const uint4* src = (const uint4*)(W4T + (size_t)e * 8192);
#pragma unroll
    for (int q = 0; q < 4; ++q) {
      int c = tid + 256 * q;
      int r = c >> 5, col = (c & 31) * 8;
      *(uint4*)&sW[r * 264 + col] = src[c];
    }
  }
  __syncthreads();
  int w = tid >> 6, l = tid & 63;
  int ml = l & 15, kq = l >> 4;
  v4f acc[2][2] = {};
  const __hip_bfloat16* Abase = H3 + (size_t)m0 * 256;
#pragma unroll
  for (int k0 = 0; k0 < 256; k0 += 32) {
    v8bf af[2], bf[2];
#pragma unroll
    for (int i = 0; i < 2; ++i) {
      int r = w * 32 + i * 16 + ml;
      int rr = r < rows ? r : 0;
      af[i] = *(const v8bf*)(Abase + (size_t)rr * 256 + k0 + kq * 8);
    }
#pragma unroll
    for (int j = 0; j < 2; ++j)
      bf[j] = *(const v8bf*)&sW[(j * 16 + ml) * 264 + k0 + kq * 8];
#pragma unroll
    for (int i = 0; i < 2; ++i)
#pragma unroll
      for (int j = 0; j < 2; ++j)
        acc[i][j] = __builtin_amdgcn_mfma_f32_16x16x32_bf16(af[i], bf[j], acc[i][j], 0, 0, 0);
  }
#pragma unroll
  for (int j = 0; j < 2; ++j) {
    int col = j * 16 + ml;
    float bs = eb4[e * 32 + col];
#pragma unroll
    for (int i = 0; i < 2; ++i) {
#pragma unroll
      for (int r = 0; r < 4; ++r) {
        int rl = w * 32 + i * 16 + kq * 4 + r;
        if (rl < rows)
          EO[(size_t)(m0 + rl) * 32 + col] = acc[i][j][r] + bs;
      }
    }
  }
}

// ---- final combine: out[row] = w0*EO[s0] + w1*EO[s1] ----
__global__ __launch_bounds__(256) void combine_out(
    const float* __restrict__ EO, const int2* __restrict__ invmap,
    const float* __restrict__ wlist, float* __restrict__ out) {
  int gid = blockIdx.x * 256 + threadIdx.x;
  int row = gid >> 3, q = (gid & 7) * 4;
  int2 s = invmap[row];
  float w0 = wlist[s.x], w1 = wlist[s.y];
  float4 a = *(const float4*)(EO + (size_t)s.x * 32 + q);
  float4 b = *(const float4*)(EO + (size_t)s.y * 32 + q);
  float4 o;
  o.x = w0 * a.x + w1 * b.x;
  o.y = w0 * a.y + w1 * b.y;
  o.z = w0 * a.z + w1 * b.z;
  o.w = w0 * a.w + w1 * b.w;
  *(float4*)(out + (size_t)row * 32 + q) = o;
}

extern "C" void kernel_launch(void* const* d_in, const int* in_sizes, int n_in,
                              void* d_out, int out_size, void* d_ws, size_t ws_size,
                              hipStream_t stream) {
  const float* obs = (const float*)d_in[0];
  const float* gw1 = (const float*)d_in[1];
  const float* gb1 = (const float*)d_in[2];
  const float* gw2 = (const float*)d_in[3];
  const float* gb2 = (const float*)d_in[4];
  const float* gw3 = (const float*)d_in[5];
  const float* gb3 = (const float*)d_in[6];
  const float* ew1 = (const float*)d_in[7];
  const float* eb1 = (const float*)d_in[8];
  const float* ew2 = (const float*)d_in[9];
  const float* eb2 = (const float*)d_in[10];
  const float* ew3 = (const float*)d_in[11];
  const float* eb3 = (const float*)d_in[12];
  const float* ew4 = (const float*)d_in[13];
  const float* eb4 = (const float*)d_in[14];

  if (ws_size < (size_t)WS_NEED) return;

  char* ws = (char*)d_ws;
  __hip_bfloat16* W1T = (__hip_bfloat16*)(ws + OFF_W1T);
  __hip_bfloat16* W2T = (__hip_bfloat16*)(ws + OFF_W2T);
  __hip_bfloat16* W3T = (__hip_bfloat16*)(ws + OFF_W3T);
  __hip_bfloat16* W4T = (__hip_bfloat16*)(ws + OFF_W4T);
  int*    meta    = (int*)(ws + OFF_META);
  int*    sel01   = (int*)(ws + OFF_SEL);
  float2* w01     = (float2*)(ws + OFF_W01);
  int*    rowlist = (int*)(ws + OFF_ROWL);
  float*  wlist   = (float*)(ws + OFF_WL);
  float*  G1      = (float*)(ws + OFF_G1);
  float*  G2      = (float*)(ws + OFF_G2);
  __hip_bfloat16* H1 = (__hip_bfloat16*)(ws + OFF_H1);
  __hip_bfloat16* H2 = (__hip_bfloat16*)(ws + OFF_H2);
  __hip_bfloat16* H3 = (__hip_bfloat16*)(ws + OFF_H3);
  float* EO       = (float*)(ws + OFF_EO);
  float* outp = (float*)d_out;

  (void)hipMemsetAsync(meta, 0, 128, stream);

  transpose_all<<<9280, 256, 0, stream>>>(ew1, ew2, ew3, ew4, W1T, W2T, W3T, W4T);

  // gating (fp32 end-to-end for exact-ish top-k)
  sgemm_elu<<<dim3(128, 4), 256, 0, stream>>>(obs, gw1, gb1, G1, B_ROWS, 256, 512);
  sgemm_elu<<<dim3(128, 2), 256, 0, stream>>>(G1, gw2, gb2, G2, B_ROWS, 128, 256);
  gate3_topk<<<256, 256, 0, stream>>>(G2, gw3, gb3, sel01, w01, meta);
  build_tiles<<<1, 64, 0, stream>>>(meta);
  scatter_rows<<<64, 256, 0, stream>>>(sel01, w01, meta, rowlist, wlist);

  // grouped expert GEMMs (bf16 MFMA); L1 gathers obs rows directly
  moe_gemm_l1<<<dim3(8, MAXTILES), 256, 0, stream>>>(obs, W1T, eb1, H1, rowlist, meta, 1024, 512);
  moe_gemm<<<dim3(4, MAXTILES), 256, 0, stream>>>(H1, W2T, eb2, H2, meta, 512, 1024);
  moe_gemm<<<dim3(2, MAXTILES), 256, 0, stream>>>(H2, W3T, eb3, H3, meta, 256, 512);
  l4_gemm<<<MAXTILES, 256, 0, stream>>>(H3, W4T, eb4, meta, EO);
  combine_out<<<512, 256, 0, stream>>>(EO, (const int2*)w01, wlist, outp);
}

// Round 5
// 481.358 us; speedup vs baseline: 1.0443x; 1.0443x over previous
//
#include <hip/hip_runtime.h>
#include <hip/hip_bf16.h>

typedef __bf16 v8bf __attribute__((ext_vector_type(8)));
typedef float  v4f  __attribute__((ext_vector_type(4)));
typedef unsigned int v4u __attribute__((ext_vector_type(4)));

#define B_ROWS 16384
#define NSLOTS 32768
#define MAXTILES 264   // 33 * 8
#define CSTRIDE 136    // C-stage LDS row stride (bf16) -> 272 B, 16B-aligned rows

// ---- workspace layout (bytes) ----
#define OFF_W1T   0u                    // [8][1024][512] bf16
#define OFF_W2T   8388608u              // [8][512][1024] bf16
#define OFF_W3T   16777216u             // [8][256][512] bf16
#define OFF_W4T   18874368u             // [8][32][256] bf16
#define OFF_META  19005440u             // ints, 4KB
#define OFF_SEL   19009536u             // int[16384]
#define OFF_W01   19075072u             // float2[16384]; reused as int2 invmap after scatter
#define OFF_ROWL  19206144u             // int[32768]
#define OFF_WL    19337216u             // float[32768]
#define OFF_Q     19468288u             // union region: G1+G2 | X1 | H2 | EO
#define OFF_G1    OFF_Q                 // [16384][256] f32
#define OFF_G2    (OFF_Q + 16777216u)   // [16384][128] f32
#define OFF_X1    OFF_Q                 // [32768][512] bf16
#define OFF_H2    OFF_Q                 // [32768][512] bf16 (X1 dead after L1)
#define OFF_EO    OFF_Q                 // [32768][32] f32 (after H2 dead)
#define OFF_H1    (OFF_Q + 33554432u)   // [32768][1024] bf16  (H3 aliases)
#define OFF_H3    OFF_H1                // [32768][256] bf16
#define WS_NEED   (OFF_H1 + 67108864u)

// NOTE: X1 aliases H2's region, and H2 is written by the L2 GEMM while X1 is
// read — NOT allowed. Give X1 its own spot: it fits after G2 is dead? G1/G2
// are dead after gate3_topk, X1 written after scatter -> safe to alias G1
// region (16 MB needed for X1 32 MB? no). X1 = 32 MB; G1+G2 = 24 MB. Use
// OFF_Q..+32MB for X1 (covers G1+G2, both dead), and H2 gets its own region
// after H1: see OFF_H2B.
#undef  OFF_H2
#undef  OFF_EO
#define OFF_H2B   (OFF_H1 + 67108864u)  // [32768][512] bf16 = 32 MB
#define OFF_EO2   OFF_Q                 // [32768][32] f32 (X1 dead after L1... but
                                        //  X1 dead only after L1; EO written at l4 — safe)
#undef  WS_NEED
#define WS_NEED   (OFF_H2B + 33554432u) // ~151 MB

// meta[] int layout: [0]=n_tiles [1..8]=counts [9..16]=cursor [17..24]=base
// [32..295]=tile_expert [296..559]=tile_m0 [560..823]=tile_rows

__device__ __forceinline__ void gload_lds16(const void* g, void* l) {
  __builtin_amdgcn_global_load_lds(
      (const __attribute__((address_space(1))) void*)g,
      (__attribute__((address_space(3))) void*)l, 16, 0, 0);
}

__device__ __forceinline__ float elu_f(float x) {
  return x > 0.f ? x : expm1f(x);
}

// ---- all weight transposes fp32 [E][R][C] -> bf16 [E][C][R] in one launch ----
__global__ __launch_bounds__(256) void transpose_all(
    const float* __restrict__ ew1, const float* __restrict__ ew2,
    const float* __restrict__ ew3, const float* __restrict__ ew4,
    __hip_bfloat16* __restrict__ W1T, __hip_bfloat16* __restrict__ W2T,
    __hip_bfloat16* __restrict__ W3T, __hip_bfloat16* __restrict__ W4T) {
  __shared__ __align__(16) float tile[32][33];
  int b = blockIdx.x;
  const float* src; __hip_bfloat16* dst; int R, C, gxs, tps, idx;
  if (b < 4096)      { src = ew1; dst = W1T; R = 512;  C = 1024; gxs = 4; tps = 9; idx = b; }
  else if (b < 8192) { src = ew2; dst = W2T; R = 1024; C = 512;  gxs = 5; tps = 9; idx = b - 4096; }
  else if (b < 9216) { src = ew3; dst = W3T; R = 512;  C = 256;  gxs = 4; tps = 7; idx = b - 8192; }
  else               { src = ew4; dst = W4T; R = 256;  C = 32;   gxs = 3; tps = 3; idx = b - 9216; }
  int e = idx >> tps, tt = idx & ((1 << tps) - 1);
  int r0 = (tt & ((1 << gxs) - 1)) * 32, c0 = (tt >> gxs) * 32;
  src += (size_t)e * R * C;
  dst += (size_t)e * R * C;
  int tr = threadIdx.x >> 5, tc = threadIdx.x & 31;
#pragma unroll
  for (int q = 0; q < 4; ++q)
    tile[tr + 8*q][tc] = src[(size_t)(r0 + tr + 8*q) * C + c0 + tc];
  __syncthreads();
#pragma unroll
  for (int q = 0; q < 4; ++q)
    dst[(size_t)(c0 + tr + 8*q) * R + r0 + tc] = __float2bfloat16(tile[tc][tr + 8*q]);
}

// ---- fp32 SGEMM + bias + ELU ----
__global__ __launch_bounds__(256) void sgemm_elu(
    const float* __restrict__ A, const float* __restrict__ Bm,
    const float* __restrict__ bias, float* __restrict__ C,
    int M, int N, int K) {
  __shared__ __align__(16) float sA[16][132];
  __shared__ __align__(16) float sB[16][68];
  int tid = threadIdx.x;
  int tx = tid & 15, ty = tid >> 4;
  int m0 = blockIdx.x * 128, n0 = blockIdx.y * 64;
  float acc[8][4] = {};
  for (int k0 = 0; k0 < K; k0 += 16) {
    {
      int m = tid >> 1, ks = (tid & 1) * 8;
      const float* ap = &A[(size_t)(m0 + m) * K + k0 + ks];
      float4 v0 = *(const float4*)ap;
      float4 v1 = *(const float4*)(ap + 4);
      sA[ks+0][m] = v0.x; sA[ks+1][m] = v0.y; sA[ks+2][m] = v0.z; sA[ks+3][m] = v0.w;
      sA[ks+4][m] = v1.x; sA[ks+5][m] = v1.y; sA[ks+6][m] = v1.z; sA[ks+7][m] = v1.w;
    }
    {
      int kr = tid >> 4, nn = (tid & 15) * 4;
      *(float4*)&sB[kr][nn] = *(const float4*)&Bm[(size_t)(k0 + kr) * N + n0 + nn];
    }
    __syncthreads();
#pragma unroll
    for (int kk = 0; kk < 16; ++kk) {
      float a[8], b[4];
      *(float4*)&a[0] = *(const float4*)&sA[kk][ty*8];
      *(float4*)&a[4] = *(const float4*)&sA[kk][ty*8+4];
      *(float4*)&b[0] = *(const float4*)&sB[kk][tx*4];
#pragma unroll
      for (int i = 0; i < 8; ++i)
#pragma unroll
        for (int j = 0; j < 4; ++j)
          acc[i][j] = fmaf(a[i], b[j], acc[i][j]);
    }
    __syncthreads();
  }
  float bs[4];
#pragma unroll
  for (int j = 0; j < 4; ++j) bs[j] = bias[n0 + tx*4 + j];
#pragma unroll
  for (int i = 0; i < 8; ++i) {
    int m = m0 + ty*8 + i;
    float4 o;
    o.x = elu_f(acc[i][0] + bs[0]);
    o.y = elu_f(acc[i][1] + bs[1]);
    o.z = elu_f(acc[i][2] + bs[2]);
    o.w = elu_f(acc[i][3] + bs[3]);
    *(float4*)&C[(size_t)m * N + n0 + tx*4] = o;
  }
}

// ---- gate layer 3 + softmax + top2 + renorm + counts ----
__global__ __launch_bounds__(256) void gate3_topk(
    const float* __restrict__ G2, const float* __restrict__ gw3,
    const float* __restrict__ gb3, int* __restrict__ sel01,
    float2* __restrict__ w01, int* __restrict__ meta) {
  __shared__ __align__(16) float g2t[64][132];
  __shared__ __align__(16) float w3[1024];
  __shared__ float b3[8];
  __shared__ int lc[8];
  int tid = threadIdx.x;
  int row0 = blockIdx.x * 64;
  {
    int r = tid >> 5, f = (tid & 31) * 4;
#pragma unroll
    for (int rr = 0; rr < 64; rr += 8)
      *(float4*)&g2t[r + rr][f] = *(const float4*)&G2[(size_t)(row0 + r + rr) * 128 + f];
  }
  ((float4*)w3)[tid] = ((const float4*)gw3)[tid];
  if (tid < 8) { b3[tid] = gb3[tid]; lc[tid] = 0; }
  __syncthreads();
  if (tid < 64) {
    int row = row0 + tid;
    float lg[8];
#pragma unroll
    for (int e = 0; e < 8; ++e) lg[e] = b3[e];
    for (int k = 0; k < 128; ++k) {
      float x = g2t[tid][k];
#pragma unroll
      for (int e = 0; e < 8; ++e) lg[e] = fmaf(x, w3[k*8 + e], lg[e]);
    }
    float mx = lg[0];
#pragma unroll
    for (int e = 1; e < 8; ++e) mx = fmaxf(mx, lg[e]);
    float p[8], s = 0.f;
#pragma unroll
    for (int e = 0; e < 8; ++e) { p[e] = expf(lg[e] - mx); s += p[e]; }
    float inv = 1.f / s;
#pragma unroll
    for (int e = 0; e < 8; ++e) p[e] *= inv;
    int i0 = 0; float v0 = p[0];
#pragma unroll
    for (int e = 1; e < 8; ++e) if (p[e] > v0) { v0 = p[e]; i0 = e; }
    int i1 = -1; float v1 = -1.f;
#pragma unroll
    for (int e = 0; e < 8; ++e) if (e != i0 && p[e] > v1) { v1 = p[e]; i1 = e; }
    float sw = 1.f / (v0 + v1);
    sel01[row] = i0 | (i1 << 8);
    w01[row] = make_float2(v0 * sw, v1 * sw);
    atomicAdd(&lc[i0], 1);
    atomicAdd(&lc[i1], 1);
  }
  __syncthreads();
  if (tid < 8) atomicAdd(&meta[1 + tid], lc[tid]);
}

// ---- prefix + tile table (single thread) ----
__global__ void build_tiles(int* __restrict__ meta) {
  if (threadIdx.x != 0) return;
  int base = 0, nt = 0;
  for (int e = 0; e < 8; ++e) {
    int c = meta[1 + e];
    meta[17 + e] = base;
    for (int j = 0; j < c; j += 128) {
      meta[32 + nt]  = e;
      meta[296 + nt] = base + j;
      meta[560 + nt] = (c - j < 128) ? (c - j) : 128;
      nt++;
    }
    base += c;
  }
  meta[0] = nt;
}

// ---- scatter rows into per-expert slot lists; also emit row->slots inverse map ----
__global__ __launch_bounds__(256) void scatter_rows(
    const int* __restrict__ sel01, float2* __restrict__ w01,
    int* __restrict__ meta, int* __restrict__ rowlist, float* __restrict__ wlist) {
  __shared__ int lc[8];
  __shared__ int gb[8];
  int tid = threadIdx.x;
  if (tid < 8) lc[tid] = 0;
  __syncthreads();
  int row = blockIdx.x * 256 + tid;
  int s = sel01[row];
  int e0 = s & 255, e1 = (s >> 8) & 255;
  float2 w = w01[row];
  int l0 = atomicAdd(&lc[e0], 1);
  int l1 = atomicAdd(&lc[e1], 1);
  __syncthreads();
  if (tid < 8) gb[tid] = atomicAdd(&meta[9 + tid], lc[tid]);
  __syncthreads();
  int s0 = meta[17 + e0] + gb[e0] + l0;
  int s1 = meta[17 + e1] + gb[e1] + l1;
  rowlist[s0] = row; wlist[s0] = w.x;
  rowlist[s1] = row; wlist[s1] = w.y;
  ((int2*)w01)[row] = make_int2(s0, s1);
}

// ---- gather obs rows into bf16 X1 [slot][512] ----
__global__ __launch_bounds__(256) void gather_convert(
    const float* __restrict__ obs, const int* __restrict__ rowlist,
    __hip_bfloat16* __restrict__ X1) {
  int tid = threadIdx.x;
  int slot = blockIdx.x * 4 + (tid >> 6);
  int l = tid & 63;
  int row = rowlist[slot];
  const float* src = obs + (size_t)row * 512 + l * 8;
  float4 a = *(const float4*)src;
  float4 b = *(const float4*)(src + 4);
  union { __hip_bfloat16 h[8]; v4u u; } t;
  t.h[0] = __float2bfloat16(a.x); t.h[1] = __float2bfloat16(a.y);
  t.h[2] = __float2bfloat16(a.z); t.h[3] = __float2bfloat16(a.w);
  t.h[4] = __float2bfloat16(b.x); t.h[5] = __float2bfloat16(b.y);
  t.h[6] = __float2bfloat16(b.z); t.h[7] = __float2bfloat16(b.w);
  *(v4u*)(X1 + (size_t)slot * 512 + l * 8) = t.u;
}

// ================= grouped MFMA GEMM: 128x128 tile, BK=32 ====================
// 1D grid, XCD-aware swizzle: id = (m*NB + j)*8 + c -> tile = 8m + c (on XCD c),
// n-block = j. The NB n-blocks of a tile share XCD c's L2 and are temporally
// adjacent -> A-tile is fetched from HBM once per tile.
// Epilogue staged through LDS (64 rows at a time) -> 16B nontemporal stores.
__global__ __launch_bounds__(256) void moe_gemm(
    const __hip_bfloat16* __restrict__ A, const __hip_bfloat16* __restrict__ BT,
    const float* __restrict__ bias, __hip_bfloat16* __restrict__ C,
    const int* __restrict__ meta, int N, int K, int lgNB) {
  int b = blockIdx.x;
  int c = b & 7;
  int j = (b >> 3) & ((1 << lgNB) - 1);
  int m = b >> (3 + lgNB);
  int t = m * 8 + c;
  if (t >= meta[0]) return;
  int e    = meta[32 + t];
  int m0   = meta[296 + t];
  int rows = meta[560 + t];
  int n0   = j * 128;

  __shared__ __align__(16) char smem[CSTRIDE * 64 * 2 > 16384 ? CSTRIDE * 64 * 2 : 16384];
  __hip_bfloat16* sA  = (__hip_bfloat16*)smem;          // 8 KB
  __hip_bfloat16* sB  = (__hip_bfloat16*)(smem + 8192); // 8 KB
  __hip_bfloat16* cst = (__hip_bfloat16*)smem;          // 17 KB epilogue stage

  int tid = threadIdx.x;
  int w = tid >> 6, l = tid & 63;
  int lr = l >> 2;
  int lk = (l & 3) * 8;
  int wm = w >> 1, wn = w & 1;
  int ml = l & 15, kq = l >> 4;

  const __hip_bfloat16* BTe = BT + (size_t)e * N * K;
  v4f acc[4][4] = {};

  for (int k0 = 0; k0 < K; k0 += 32) {
#pragma unroll
    for (int it = 0; it < 2; ++it) {
      int r = it * 64 + w * 16 + lr;
      int gr = m0 + (r < rows ? r : rows - 1);
      gload_lds16(A + (size_t)gr * K + k0 + lk, &sA[(it * 64 + w * 16) * 32]);
    }
#pragma unroll
    for (int it = 0; it < 2; ++it) {
      int r = it * 64 + w * 16 + lr;
      gload_lds16(BTe + (size_t)(n0 + r) * K + k0 + lk, &sB[(it * 64 + w * 16) * 32]);
    }
    __syncthreads();
    v8bf af[4], bf[4];
#pragma unroll
    for (int i = 0; i < 4; ++i)
      af[i] = *(const v8bf*)&sA[(wm * 64 + i * 16 + ml) * 32 + kq * 8];
#pragma unroll
    for (int jj = 0; jj < 4; ++jj)
      bf[jj] = *(const v8bf*)&sB[(wn * 64 + jj * 16 + ml) * 32 + kq * 8];
#pragma unroll
    for (int i = 0; i < 4; ++i)
#pragma unroll
      for (int jj = 0; jj < 4; ++jj)
        acc[i][jj] = __builtin_amdgcn_mfma_f32_16x16x32_bf16(af[i], bf[jj], acc[i][jj], 0, 0, 0);
    __syncthreads();
  }

  float bs[4];
#pragma unroll
  for (int jj = 0; jj < 4; ++jj)
    bs[jj] = bias[(size_t)e * N + n0 + wn * 64 + jj * 16 + ml];

#pragma unroll
  for (int h = 0; h < 2; ++h) {
    if (wm == h) {
#pragma unroll
      for (int i = 0; i < 4; ++i)
#pragma unroll
        for (int jj = 0; jj < 4; ++jj)
#pragma unroll
          for (int r = 0; r < 4; ++r)
            cst[(i * 16 + kq * 4 + r) * CSTRIDE + wn * 64 + jj * 16 + ml] =
                __float2bfloat16(elu_f(acc[i][jj][r] + bs[jj]));
    }
    __syncthreads();
#pragma unroll
    for (int q = 0; q < 4; ++q) {
      int z = q * 256 + tid;
      int row = z >> 4, ch = z & 15;
      int rl = h * 64 + row;
      if (rl < rows) {
        v4u v = *(const v4u*)&cst[row * CSTRIDE + ch * 8];
        __builtin_nontemporal_store(
            v, (v4u*)&C[(size_t)(m0 + rl) * N + n0 + ch * 8]);
      }
    }
    __syncthreads();
  }
}

// ---- L4 as grouped MFMA GEMM: EO[slot][32] = H3[slot][256] @ W4T[e][32][256]^T + eb4 ----
__global__ __launch_bounds__(256) void l4_gemm(
    const __hip_bfloat16* __restrict__ H3, const __hip_bfloat16* __restrict__ W4T,
    const float* __restrict__ eb4, const int* __restrict__ meta,
    float* __restrict__ EO) {
  int t = blockIdx.x;
  if (t >= meta[0]) return;
  int e = meta[32 + t], m0 = meta[296 + t], rows = meta[560 + t];
  __shared__ __align__(16) __hip_bfloat16 sW[32 * 264];
  int tid = threadIdx.x;
  {
    const uint4* src = (const uint4*)(W4T + (size_t)e * 8192);
#pragma unroll
    for (int q = 0; q < 4; ++q) {
      int c = tid + 256 * q;
      int r = c >> 5, col = (c & 31) * 8;
      *(uint4*)&sW[r * 264 + col] = src[c];
    }
  }
  __syncthreads();
  int w = tid >> 6, l = tid & 63;
  int ml = l & 15, kq = l >> 4;
  v4f acc[2][2] = {};
  const __hip_bfloat16* Abase = H3 + (size_t)m0 * 256;
#pragma unroll
  for (int k0 = 0; k0 < 256; k0 += 32) {
    v8bf af[2], bf[2];
#pragma unroll
    for (int i = 0; i < 2; ++i) {
      int r = w * 32 + i * 16 + ml;
      int rr = r < rows ? r : 0;
      af[i] = *(const v8bf*)(Abase + (size_t)rr * 256 + k0 + kq * 8);
    }
#pragma unroll
    for (int j = 0; j < 2; ++j)
      bf[j] = *(const v8bf*)&sW[(j * 16 + ml) * 264 + k0 + kq * 8];
#pragma unroll
    for (int i = 0; i < 2; ++i)
#pragma unroll
      for (int j = 0; j < 2; ++j)
        acc[i][j] = __builtin_amdgcn_mfma_f32_16x16x32_bf16(af[i], bf[j], acc[i][j], 0, 0, 0);
  }
#pragma unroll
  for (int j = 0; j < 2; ++j) {
    int col = j * 16 + ml;
    float bs = eb4[e * 32 + col];
#pragma unroll
    for (int i = 0; i < 2; ++i) {
#pragma unroll
      for (int r = 0; r < 4; ++r) {
        int rl = w * 32 + i * 16 + kq * 4 + r;
        if (rl < rows)
          EO[(size_t)(m0 + rl) * 32 + col] = acc[i][j][r] + bs;
      }
    }
  }
}

// ---- final combine: out[row] = w0*EO[s0] + w1*EO[s1] ----
__global__ __launch_bounds__(256) void combine_out(
    const float* __restrict__ EO, const int2* __restrict__ invmap,
    const float* __restrict__ wlist, float* __restrict__ out) {
  int gid = blockIdx.x * 256 + threadIdx.x;
  int row = gid >> 3, q = (gid & 7) * 4;
  int2 s = invmap[row];
  float w0 = wlist[s.x], w1 = wlist[s.y];
  float4 a = *(const float4*)(EO + (size_t)s.x * 32 + q);
  float4 b = *(const float4*)(EO + (size_t)s.y * 32 + q);
  float4 o;
  o.x = w0 * a.x + w1 * b.x;
  o.y = w0 * a.y + w1 * b.y;
  o.z = w0 * a.z + w1 * b.z;
  o.w = w0 * a.w + w1 * b.w;
  *(float4*)(out + (size_t)row * 32 + q) = o;
}

extern "C" void kernel_launch(void* const* d_in, const int* in_sizes, int n_in,
                              void* d_out, int out_size, void* d_ws, size_t ws_size,
                              hipStream_t stream) {
  const float* obs = (const float*)d_in[0];
  const float* gw1 = (const float*)d_in[1];
  const float* gb1 = (const float*)d_in[2];
  const float* gw2 = (const float*)d_in[3];
  const float* gb2 = (const float*)d_in[4];
  const float* gw3 = (const float*)d_in[5];
  const float* gb3 = (const float*)d_in[6];
  const float* ew1 = (const float*)d_in[7];
  const float* eb1 = (const float*)d_in[8];
  const float* ew2 = (const float*)d_in[9];
  const float* eb2 = (const float*)d_in[10];
  const float* ew3 = (const float*)d_in[11];
  const float* eb3 = (const float*)d_in[12];
  const float* ew4 = (const float*)d_in[13];
  const float* eb4 = (const float*)d_in[14];

  if (ws_size < (size_t)WS_NEED) return;

  char* ws = (char*)d_ws;
  __hip_bfloat16* W1T = (__hip_bfloat16*)(ws + OFF_W1T);
  __hip_bfloat16* W2T = (__hip_bfloat16*)(ws + OFF_W2T);
  __hip_bfloat16* W3T = (__hip_bfloat16*)(ws + OFF_W3T);
  __hip_bfloat16* W4T = (__hip_bfloat16*)(ws + OFF_W4T);
  int*    meta    = (int*)(ws + OFF_META);
  int*    sel01   = (int*)(ws + OFF_SEL);
  float2* w01     = (float2*)(ws + OFF_W01);
  int*    rowlist = (int*)(ws + OFF_ROWL);
  float*  wlist   = (float*)(ws + OFF_WL);
  float*  G1      = (float*)(ws + OFF_G1);
  float*  G2      = (float*)(ws + OFF_G2);
  __hip_bfloat16* X1 = (__hip_bfloat16*)(ws + OFF_X1);   // aliases G1/G2 (dead)
  __hip_bfloat16* H1 = (__hip_bfloat16*)(ws + OFF_H1);
  __hip_bfloat16* H2 = (__hip_bfloat16*)(ws + OFF_H2B);
  __hip_bfloat16* H3 = (__hip_bfloat16*)(ws + OFF_H3);   // aliases H1 region
  float* EO       = (float*)(ws + OFF_EO2);              // aliases X1 (dead after L1)
  float* outp = (float*)d_out;

  (void)hipMemsetAsync(meta, 0, 128, stream);

  transpose_all<<<9280, 256, 0, stream>>>(ew1, ew2, ew3, ew4, W1T, W2T, W3T, W4T);

  // gating (fp32 end-to-end for exact-ish top-k)
  sgemm_elu<<<dim3(128, 4), 256, 0, stream>>>(obs, gw1, gb1, G1, B_ROWS, 256, 512);
  sgemm_elu<<<dim3(128, 2), 256, 0, stream>>>(G1, gw2, gb2, G2, B_ROWS, 128, 256);
  gate3_topk<<<256, 256, 0, stream>>>(G2, gw3, gb3, sel01, w01, meta);
  build_tiles<<<1, 64, 0, stream>>>(meta);
  scatter_rows<<<64, 256, 0, stream>>>(sel01, w01, meta, rowlist, wlist);
  gather_convert<<<8192, 256, 0, stream>>>(obs, rowlist, X1);

  // grouped expert GEMMs (bf16 MFMA), XCD-swizzled 1D grids
  moe_gemm<<<MAXTILES * 8, 256, 0, stream>>>(X1, W1T, eb1, H1, meta, 1024, 512, 3);
  moe_gemm<<<MAXTILES * 4, 256, 0, stream>>>(H1, W2T, eb2, H2, meta, 512, 1024, 2);
  moe_gemm<<<MAXTILES * 2, 256, 0, stream>>>(H2, W3T, eb3, H3, meta, 256, 512, 1);
  l4_gemm<<<MAXTILES, 256, 0, stream>>>(H3, W4T, eb4, meta, EO);
  combine_out<<<512, 256, 0, stream>>>(EO, (const int2*)w01, wlist, outp);
}

// Round 6
// 460.427 us; speedup vs baseline: 1.0917x; 1.0455x over previous
//
#include <hip/hip_runtime.h>
#include <hip/hip_bf16.h>

typedef __bf16 v8bf __attribute__((ext_vector_type(8)));
typedef float  v4f  __attribute__((ext_vector_type(4)));
typedef unsigned int v4u __attribute__((ext_vector_type(4)));

#define B_ROWS 16384
#define NSLOTS 32768
#define MAXTILES 264   // 33 * 8
#define CSTRIDE 136    // C-stage LDS row stride (bf16) -> 272 B, 16B-aligned rows

// ---- workspace layout (bytes) ----
#define OFF_W1T   0u                    // [8][1024][512] bf16
#define OFF_W2T   8388608u              // [8][512][1024] bf16
#define OFF_W3T   16777216u             // [8][256][512] bf16
#define OFF_W4T   18874368u             // [8][32][256] bf16
#define OFF_META  19005440u             // ints, 4KB
#define OFF_SEL   19009536u             // int[16384]
#define OFF_W01   19075072u             // float2[16384]; reused as int2 invmap after scatter
#define OFF_ROWL  19206144u             // int[32768]
#define OFF_WL    19337216u             // float[32768]
#define OFF_Q     19468288u             // union: G1+G2 (gating) -> X1 -> EO
#define OFF_G1    OFF_Q                 // [16384][256] f32
#define OFF_G2    (OFF_Q + 16777216u)   // [16384][128] f32
#define OFF_X1    OFF_Q                 // [32768][512] bf16 (G1/G2 dead)
#define OFF_EO2   OFF_Q                 // [32768][32] f32 (X1 dead after L1... EO written at l4)
#define OFF_H1    (OFF_Q + 33554432u)   // [32768][1024] bf16  (H3 aliases)
#define OFF_H3    OFF_H1                // [32768][256] bf16
#define OFF_H2B   (OFF_H1 + 67108864u)  // [32768][512] bf16
#define WS_NEED   (OFF_H2B + 33554432u) // ~151 MB

// meta[] int layout: [0]=n_tiles [1..8]=counts [9..16]=cursor [17..24]=base
// [32..295]=tile_expert [296..559]=tile_m0 [560..823]=tile_rows

__device__ __forceinline__ void gload_lds16(const void* g, void* l) {
  __builtin_amdgcn_global_load_lds(
      (const __attribute__((address_space(1))) void*)g,
      (__attribute__((address_space(3))) void*)l, 16, 0, 0);
}

__device__ __forceinline__ float elu_f(float x) {
  return x > 0.f ? x : expm1f(x);
}

// ---- all weight transposes fp32 [E][R][C] -> bf16 [E][C][R] in one launch ----
__global__ __launch_bounds__(256) void transpose_all(
    const float* __restrict__ ew1, const float* __restrict__ ew2,
    const float* __restrict__ ew3, const float* __restrict__ ew4,
    __hip_bfloat16* __restrict__ W1T, __hip_bfloat16* __restrict__ W2T,
    __hip_bfloat16* __restrict__ W3T, __hip_bfloat16* __restrict__ W4T) {
  __shared__ __align__(16) float tile[32][33];
  int b = blockIdx.x;
  const float* src; __hip_bfloat16* dst; int R, C, gxs, tps, idx;
  if (b < 4096)      { src = ew1; dst = W1T; R = 512;  C = 1024; gxs = 4; tps = 9; idx = b; }
  else if (b < 8192) { src = ew2; dst = W2T; R = 1024; C = 512;  gxs = 5; tps = 9; idx = b - 4096; }
  else if (b < 9216) { src = ew3; dst = W3T; R = 512;  C = 256;  gxs = 4; tps = 7; idx = b - 8192; }
  else               { src = ew4; dst = W4T; R = 256;  C = 32;   gxs = 3; tps = 3; idx = b - 9216; }
  int e = idx >> tps, tt = idx & ((1 << tps) - 1);
  int r0 = (tt & ((1 << gxs) - 1)) * 32, c0 = (tt >> gxs) * 32;
  src += (size_t)e * R * C;
  dst += (size_t)e * R * C;
  int tr = threadIdx.x >> 5, tc = threadIdx.x & 31;
#pragma unroll
  for (int q = 0; q < 4; ++q)
    tile[tr + 8*q][tc] = src[(size_t)(r0 + tr + 8*q) * C + c0 + tc];
  __syncthreads();
#pragma unroll
  for (int q = 0; q < 4; ++q)
    dst[(size_t)(c0 + tr + 8*q) * R + r0 + tc] = __float2bfloat16(tile[tc][tr + 8*q]);
}

// ---- fp32 SGEMM + bias + ELU ----
__global__ __launch_bounds__(256) void sgemm_elu(
    const float* __restrict__ A, const float* __restrict__ Bm,
    const float* __restrict__ bias, float* __restrict__ C,
    int M, int N, int K) {
  __shared__ __align__(16) float sA[16][132];
  __shared__ __align__(16) float sB[16][68];
  int tid = threadIdx.x;
  int tx = tid & 15, ty = tid >> 4;
  int m0 = blockIdx.x * 128, n0 = blockIdx.y * 64;
  float acc[8][4] = {};
  for (int k0 = 0; k0 < K; k0 += 16) {
    {
      int m = tid >> 1, ks = (tid & 1) * 8;
      const float* ap = &A[(size_t)(m0 + m) * K + k0 + ks];
      float4 v0 = *(const float4*)ap;
      float4 v1 = *(const float4*)(ap + 4);
      sA[ks+0][m] = v0.x; sA[ks+1][m] = v0.y; sA[ks+2][m] = v0.z; sA[ks+3][m] = v0.w;
      sA[ks+4][m] = v1.x; sA[ks+5][m] = v1.y; sA[ks+6][m] = v1.z; sA[ks+7][m] = v1.w;
    }
    {
      int kr = tid >> 4, nn = (tid & 15) * 4;
      *(float4*)&sB[kr][nn] = *(const float4*)&Bm[(size_t)(k0 + kr) * N + n0 + nn];
    }
    __syncthreads();
#pragma unroll
    for (int kk = 0; kk < 16; ++kk) {
      float a[8], b[4];
      *(float4*)&a[0] = *(const float4*)&sA[kk][ty*8];
      *(float4*)&a[4] = *(const float4*)&sA[kk][ty*8+4];
      *(float4*)&b[0] = *(const float4*)&sB[kk][tx*4];
#pragma unroll
      for (int i = 0; i < 8; ++i)
#pragma unroll
        for (int j = 0; j < 4; ++j)
          acc[i][j] = fmaf(a[i], b[j], acc[i][j]);
    }
    __syncthreads();
  }
  float bs[4];
#pragma unroll
  for (int j = 0; j < 4; ++j) bs[j] = bias[n0 + tx*4 + j];
#pragma unroll
  for (int i = 0; i < 8; ++i) {
    int m = m0 + ty*8 + i;
    float4 o;
    o.x = elu_f(acc[i][0] + bs[0]);
    o.y = elu_f(acc[i][1] + bs[1]);
    o.z = elu_f(acc[i][2] + bs[2]);
    o.w = elu_f(acc[i][3] + bs[3]);
    *(float4*)&C[(size_t)m * N + n0 + tx*4] = o;
  }
}

// ---- gate layer 3 + softmax + top2 + renorm + counts ----
__global__ __launch_bounds__(256) void gate3_topk(
    const float* __restrict__ G2, const float* __restrict__ gw3,
    const float* __restrict__ gb3, int* __restrict__ sel01,
    float2* __restrict__ w01, int* __restrict__ meta) {
  __shared__ __align__(16) float g2t[64][132];
  __shared__ __align__(16) float w3[1024];
  __shared__ float b3[8];
  __shared__ int lc[8];
  int tid = threadIdx.x;
  int row0 = blockIdx.x * 64;
  {
    int r = tid >> 5, f = (tid & 31) * 4;
#pragma unroll
    for (int rr = 0; rr < 64; rr += 8)
      *(float4*)&g2t[r + rr][f] = *(const float4*)&G2[(size_t)(row0 + r + rr) * 128 + f];
  }
  ((float4*)w3)[tid] = ((const float4*)gw3)[tid];
  if (tid < 8) { b3[tid] = gb3[tid]; lc[tid] = 0; }
  __syncthreads();
  if (tid < 64) {
    int row = row0 + tid;
    float lg[8];
#pragma unroll
    for (int e = 0; e < 8; ++e) lg[e] = b3[e];
    for (int k = 0; k < 128; ++k) {
      float x = g2t[tid][k];
#pragma unroll
      for (int e = 0; e < 8; ++e) lg[e] = fmaf(x, w3[k*8 + e], lg[e]);
    }
    float mx = lg[0];
#pragma unroll
    for (int e = 1; e < 8; ++e) mx = fmaxf(mx, lg[e]);
    float p[8], s = 0.f;
#pragma unroll
    for (int e = 0; e < 8; ++e) { p[e] = expf(lg[e] - mx); s += p[e]; }
    float inv = 1.f / s;
#pragma unroll
    for (int e = 0; e < 8; ++e) p[e] *= inv;
    int i0 = 0; float v0 = p[0];
#pragma unroll
    for (int e = 1; e < 8; ++e) if (p[e] > v0) { v0 = p[e]; i0 = e; }
    int i1 = -1; float v1 = -1.f;
#pragma unroll
    for (int e = 0; e < 8; ++e) if (e != i0 && p[e] > v1) { v1 = p[e]; i1 = e; }
    float sw = 1.f / (v0 + v1);
    sel01[row] = i0 | (i1 << 8);
    w01[row] = make_float2(v0 * sw, v1 * sw);
    atomicAdd(&lc[i0], 1);
    atomicAdd(&lc[i1], 1);
  }
  __syncthreads();
  if (tid < 8) atomicAdd(&meta[1 + tid], lc[tid]);
}

// ---- prefix + tile table (single thread) ----
__global__ void build_tiles(int* __restrict__ meta) {
  if (threadIdx.x != 0) return;
  int base = 0, nt = 0;
  for (int e = 0; e < 8; ++e) {
    int c = meta[1 + e];
    meta[17 + e] = base;
    for (int j = 0; j < c; j += 128) {
      meta[32 + nt]  = e;
      meta[296 + nt] = base + j;
      meta[560 + nt] = (c - j < 128) ? (c - j) : 128;
      nt++;
    }
    base += c;
  }
  meta[0] = nt;
}

// ---- scatter rows into per-expert slot lists; also emit row->slots inverse map ----
__global__ __launch_bounds__(256) void scatter_rows(
    const int* __restrict__ sel01, float2* __restrict__ w01,
    int* __restrict__ meta, int* __restrict__ rowlist, float* __restrict__ wlist) {
  __shared__ int lc[8];
  __shared__ int gb[8];
  int tid = threadIdx.x;
  if (tid < 8) lc[tid] = 0;
  __syncthreads();
  int row = blockIdx.x * 256 + tid;
  int s = sel01[row];
  int e0 = s & 255, e1 = (s >> 8) & 255;
  float2 w = w01[row];
  int l0 = atomicAdd(&lc[e0], 1);
  int l1 = atomicAdd(&lc[e1], 1);
  __syncthreads();
  if (tid < 8) gb[tid] = atomicAdd(&meta[9 + tid], lc[tid]);
  __syncthreads();
  int s0 = meta[17 + e0] + gb[e0] + l0;
  int s1 = meta[17 + e1] + gb[e1] + l1;
  rowlist[s0] = row; wlist[s0] = w.x;
  rowlist[s1] = row; wlist[s1] = w.y;
  ((int2*)w01)[row] = make_int2(s0, s1);
}

// ---- gather obs rows into bf16 X1 [slot][512] ----
__global__ __launch_bounds__(256) void gather_convert(
    const float* __restrict__ obs, const int* __restrict__ rowlist,
    __hip_bfloat16* __restrict__ X1) {
  int tid = threadIdx.x;
  int slot = blockIdx.x * 4 + (tid >> 6);
  int l = tid & 63;
  int row = rowlist[slot];
  const float* src = obs + (size_t)row * 512 + l * 8;
  float4 a = *(const float4*)src;
  float4 b = *(const float4*)(src + 4);
  union { __hip_bfloat16 h[8]; v4u u; } t;
  t.h[0] = __float2bfloat16(a.x); t.h[1] = __float2bfloat16(a.y);
  t.h[2] = __float2bfloat16(a.z); t.h[3] = __float2bfloat16(a.w);
  t.h[4] = __float2bfloat16(b.x); t.h[5] = __float2bfloat16(b.y);
  t.h[6] = __float2bfloat16(b.z); t.h[7] = __float2bfloat16(b.w);
  *(v4u*)(X1 + (size_t)slot * 512 + l * 8) = t.u;
}

// ================= grouped MFMA GEMM: 128x128 tile, BK=32 ====================
// XCD swizzle: id = (m*NB + j)*8 + c -> tile = 8m + c (XCD c), n-block = j.
// Double-buffered LDS (one barrier/iter): prefetch tile k+1 via
// global_load_lds while MFMA runs on tile k; the compiler's vmcnt(0) drain
// before s_barrier is the wait for the prefetch issued one full compute phase
// earlier. LDS fragment reads are XOR-swizzled (16B chunk c stored from global
// chunk c^((row>>1)&3)) -> 2 lanes/bank-group (conflict-free per m136).
__global__ __launch_bounds__(256) void moe_gemm(
    const __hip_bfloat16* __restrict__ A, const __hip_bfloat16* __restrict__ BT,
    const float* __restrict__ bias, __hip_bfloat16* __restrict__ C,
    const int* __restrict__ meta, int N, int K, int lgNB) {
  int b = blockIdx.x;
  int c = b & 7;
  int j = (b >> 3) & ((1 << lgNB) - 1);
  int m = b >> (3 + lgNB);
  int t = m * 8 + c;
  if (t >= meta[0]) return;
  int e    = meta[32 + t];
  int m0   = meta[296 + t];
  int rows = meta[560 + t];
  int n0   = j * 128;

  __shared__ __align__(16) char smem[32768];   // 2 x (8KB A + 8KB B); cst aliases
  __hip_bfloat16* cst = (__hip_bfloat16*)smem;

  int tid = threadIdx.x;
  int w = tid >> 6, l = tid & 63;
  int lr = l >> 2;                    // row-within-16
  int csw = ((l & 3) ^ ((l >> 3) & 3)) * 8;  // swizzled source K-chunk (elements)
  int wm = w >> 1, wn = w & 1;
  int ml = l & 15, kq = l >> 4;
  int key = (ml >> 1) & 3;            // fragment read swizzle key

  const __hip_bfloat16* BTe = BT + (size_t)e * N * K;
  // per-lane global row bases (hoisted)
  int ra0 = w * 16 + lr, ra1 = 64 + w * 16 + lr;
  const __hip_bfloat16* gA0 = A + (size_t)(m0 + (ra0 < rows ? ra0 : rows - 1)) * K + csw;
  const __hip_bfloat16* gA1 = A + (size_t)(m0 + (ra1 < rows ? ra1 : rows - 1)) * K + csw;
  const __hip_bfloat16* gB0 = BTe + (size_t)(n0 + ra0) * K + csw;
  const __hip_bfloat16* gB1 = BTe + (size_t)(n0 + ra1) * K + csw;

  v4f acc[4][4] = {};
  int nIter = K >> 5;

  // prologue: stage k0=0 into buffer 0
  {
    __hip_bfloat16* sA = (__hip_bfloat16*)smem;
    __hip_bfloat16* sB = (__hip_bfloat16*)(smem + 8192);
    gload_lds16(gA0, &sA[(w * 16) * 32]);
    gload_lds16(gA1, &sA[(64 + w * 16) * 32]);
    gload_lds16(gB0, &sB[(w * 16) * 32]);
    gload_lds16(gB1, &sB[(64 + w * 16) * 32]);
  }

  for (int it = 0; it < nIter; ++it) {
    __syncthreads();  // vmcnt(0): buffer it&1 ready; prev compute drained
    int cur = (it & 1) * 16384;
    if (it + 1 < nIter) {
      int nxt = ((it + 1) & 1) * 16384;
      int k0 = (it + 1) << 5;
      __hip_bfloat16* sA = (__hip_bfloat16*)(smem + nxt);
      __hip_bfloat16* sB = (__hip_bfloat16*)(smem + nxt + 8192);
      gload_lds16(gA0 + k0, &sA[(w * 16) * 32]);
      gload_lds16(gA1 + k0, &sA[(64 + w * 16) * 32]);
      gload_lds16(gB0 + k0, &sB[(w * 16) * 32]);
      gload_lds16(gB1 + k0, &sB[(64 + w * 16) * 32]);
    }
    const __hip_bfloat16* sA = (const __hip_bfloat16*)(smem + cur);
    const __hip_bfloat16* sB = (const __hip_bfloat16*)(smem + cur + 8192);
    v8bf af[4], bf[4];
#pragma unroll
    for (int i = 0; i < 4; ++i)
      af[i] = *(const v8bf*)&sA[(wm * 64 + i * 16 + ml) * 32 + ((kq ^ key)) * 8];
#pragma unroll
    for (int jj = 0; jj < 4; ++jj)
      bf[jj] = *(const v8bf*)&sB[(wn * 64 + jj * 16 + ml) * 32 + ((kq ^ key)) * 8];
#pragma unroll
    for (int i = 0; i < 4; ++i)
#pragma unroll
      for (int jj = 0; jj < 4; ++jj)
        acc[i][jj] = __builtin_amdgcn_mfma_f32_16x16x32_bf16(af[i], bf[jj], acc[i][jj], 0, 0, 0);
  }
  __syncthreads();  // last buffer's reads done before epilogue overwrites

  float bs[4];
#pragma unroll
  for (int jj = 0; jj < 4; ++jj)
    bs[jj] = bias[(size_t)e * N + n0 + wn * 64 + jj * 16 + ml];

#pragma unroll
  for (int h = 0; h < 2; ++h) {
    if (wm == h) {
#pragma unroll
      for (int i = 0; i < 4; ++i)
#pragma unroll
        for (int jj = 0; jj < 4; ++jj)
#pragma unroll
          for (int r = 0; r < 4; ++r)
            cst[(i * 16 + kq * 4 + r) * CSTRIDE + wn * 64 + jj * 16 + ml] =
                __float2bfloat16(elu_f(acc[i][jj][r] + bs[jj]));
    }
    __syncthreads();
#pragma unroll
    for (int q = 0; q < 4; ++q) {
      int z = q * 256 + tid;
      int row = z >> 4, ch = z & 15;
      int rl = h * 64 + row;
      if (rl < rows) {
        v4u v = *(const v4u*)&cst[row * CSTRIDE + ch * 8];
        __builtin_nontemporal_store(
            v, (v4u*)&C[(size_t)(m0 + rl) * N + n0 + ch * 8]);
      }
    }
    __syncthreads();
  }
}

// ---- L4 as grouped MFMA GEMM: EO[slot][32] = H3[slot][256] @ W4T[e][32][256]^T + eb4 ----
__global__ __launch_bounds__(256) void l4_gemm(
    const __hip_bfloat16* __restrict__ H3, const __hip_bfloat16* __restrict__ W4T,
    const float* __restrict__ eb4, const int* __restrict__ meta,
    float* __restrict__ EO) {
  int t = blockIdx.x;
  if (t >= meta[0]) return;
  int e = meta[32 + t], m0 = meta[296 + t], rows = meta[560 + t];
  __shared__ __align__(16) __hip_bfloat16 sW[32 * 264];
  int tid = threadIdx.x;
  {
    const uint4* src = (const uint4*)(W4T + (size_t)e * 8192);
#pragma unroll
    for (int q = 0; q < 4; ++q) {
      int c = tid + 256 * q;
      int r = c >> 5, col = (c & 31) * 8;
      *(uint4*)&sW[r * 264 + col] = src[c];
    }
  }
  __syncthreads();
  int w = tid >> 6, l = tid & 63;
  int ml = l & 15, kq = l >> 4;
  v4f acc[2][2] = {};
  const __hip_bfloat16* Abase = H3 + (size_t)m0 * 256;
#pragma unroll
  for (int k0 = 0; k0 < 256; k0 += 32) {
    v8bf af[2], bf[2];
#pragma unroll
    for (int i = 0; i < 2; ++i) {
      int r = w * 32 + i * 16 + ml;
      int rr = r < rows ? r : 0;
      af[i] = *(const v8bf*)(Abase + (size_t)rr * 256 + k0 + kq * 8);
    }
#pragma unroll
    for (int j = 0; j < 2; ++j)
      bf[j] = *(const v8bf*)&sW[(j * 16 + ml) * 264 + k0 + kq * 8];
#pragma unroll
    for (int i = 0; i < 2; ++i)
#pragma unroll
      for (int j = 0; j < 2; ++j)
        acc[i][j] = __builtin_amdgcn_mfma_f32_16x16x32_bf16(af[i], bf[j], acc[i][j], 0, 0, 0);
  }
#pragma unroll
  for (int j = 0; j < 2; ++j) {
    int col = j * 16 + ml;
    float bs = eb4[e * 32 + col];
#pragma unroll
    for (int i = 0; i < 2; ++i) {
#pragma unroll
      for (int r = 0; r < 4; ++r) {
        int rl = w * 32 + i * 16 + kq * 4 + r;
        if (rl < rows)
          EO[(size_t)(m0 + rl) * 32 + col] = acc[i][j][r] + bs;
      }
    }
  }
}

// ---- final combine: out[row] = w0*EO[s0] + w1*EO[s1] ----
__global__ __launch_bounds__(256) void combine_out(
    const float* __restrict__ EO, const int2* __restrict__ invmap,
    const float* __restrict__ wlist, float* __restrict__ out) {
  int gid = blockIdx.x * 256 + threadIdx.x;
  int row = gid >> 3, q = (gid & 7) * 4;
  int2 s = invmap[row];
  float w0 = wlist[s.x], w1 = wlist[s.y];
  float4 a = *(const float4*)(EO + (size_t)s.x * 32 + q);
  float4 b = *(const float4*)(EO + (size_t)s.y * 32 + q);
  float4 o;
  o.x = w0 * a.x + w1 * b.x;
  o.y = w0 * a.y + w1 * b.y;
  o.z = w0 * a.z + w1 * b.z;
  o.w = w0 * a.w + w1 * b.w;
  *(float4*)(out + (size_t)row * 32 + q) = o;
}

extern "C" void kernel_launch(void* const* d_in, const int* in_sizes, int n_in,
                              void* d_out, int out_size, void* d_ws, size_t ws_size,
                              hipStream_t stream) {
  const float* obs = (const float*)d_in[0];
  const float* gw1 = (const float*)d_in[1];
  const float* gb1 = (const float*)d_in[2];
  const float* gw2 = (const float*)d_in[3];
  const float* gb2 = (const float*)d_in[4];
  const float* gw3 = (const float*)d_in[5];
  const float* gb3 = (const float*)d_in[6];
  const float* ew1 = (const float*)d_in[7];
  const float* eb1 = (const float*)d_in[8];
  const float* ew2 = (const float*)d_in[9];
  const float* eb2 = (const float*)d_in[10];
  const float* ew3 = (const float*)d_in[11];
  const float* eb3 = (const float*)d_in[12];
  const float* ew4 = (const float*)d_in[13];
  const float* eb4 = (const float*)d_in[14];

  if (ws_size < (size_t)WS_NEED) return;

  char* ws = (char*)d_ws;
  __hip_bfloat16* W1T = (__hip_bfloat16*)(ws + OFF_W1T);
  __hip_bfloat16* W2T = (__hip_bfloat16*)(ws + OFF_W2T);
  __hip_bfloat16* W3T = (__hip_bfloat16*)(ws + OFF_W3T);
  __hip_bfloat16* W4T = (__hip_bfloat16*)(ws + OFF_W4T);
  int*    meta    = (int*)(ws + OFF_META);
  int*    sel01   = (int*)(ws + OFF_SEL);
  float2* w01     = (float2*)(ws + OFF_W01);
  int*    rowlist = (int*)(ws + OFF_ROWL);
  float*  wlist   = (float*)(ws + OFF_WL);
  float*  G1      = (float*)(ws + OFF_G1);
  float*  G2      = (float*)(ws + OFF_G2);
  __hip_bfloat16* X1 = (__hip_bfloat16*)(ws + OFF_X1);   // aliases G1/G2 (dead)
  __hip_bfloat16* H1 = (__hip_bfloat16*)(ws + OFF_H1);
  __hip_bfloat16* H2 = (__hip_bfloat16*)(ws + OFF_H2B);
  __hip_bfloat16* H3 = (__hip_bfloat16*)(ws + OFF_H3);   // aliases H1 region
  float* EO       = (float*)(ws + OFF_EO2);              // aliases X1 (dead after L1)
  float* outp = (float*)d_out;

  (void)hipMemsetAsync(meta, 0, 128, stream);

  transpose_all<<<9280, 256, 0, stream>>>(ew1, ew2, ew3, ew4, W1T, W2T, W3T, W4T);

  // gating (fp32 end-to-end for exact-ish top-k)
  sgemm_elu<<<dim3(128, 4), 256, 0, stream>>>(obs, gw1, gb1, G1, B_ROWS, 256, 512);
  sgemm_elu<<<dim3(128, 2), 256, 0, stream>>>(G1, gw2, gb2, G2, B_ROWS, 128, 256);
  gate3_topk<<<256, 256, 0, stream>>>(G2, gw3, gb3, sel01, w01, meta);
  build_tiles<<<1, 64, 0, stream>>>(meta);
  scatter_rows<<<64, 256, 0, stream>>>(sel01, w01, meta, rowlist, wlist);
  gather_convert<<<8192, 256, 0, stream>>>(obs, rowlist, X1);

  // grouped expert GEMMs (bf16 MFMA), XCD-swizzled 1D grids, dbuf K-loop
  moe_gemm<<<MAXTILES * 8, 256, 0, stream>>>(X1, W1T, eb1, H1, meta, 1024, 512, 3);
  moe_gemm<<<MAXTILES * 4, 256, 0, stream>>>(H1, W2T, eb2, H2, meta, 512, 1024, 2);
  moe_gemm<<<MAXTILES * 2, 256, 0, stream>>>(H2, W3T, eb3, H3, meta, 256, 512, 1);
  l4_gemm<<<MAXTILES, 256, 0, stream>>>(H3, W4T, eb4, meta, EO);
  combine_out<<<512, 256, 0, stream>>>(EO, (const int2*)w01, wlist, outp);
}